// Round 4
// baseline (690.329 us; speedup 1.0000x reference)
//
#include <hip/hip_runtime.h>
#include <hip/hip_bf16.h>

#define S_LEN 2048
#define BATCH 8
#define HID   1024
#define NP    3072      // permuted gate dim: i,g,o only (f is dead in reference)
#define MROWS 16384     // S*B

using bf16x8 = __attribute__((ext_vector_type(8))) short;
using f32x4  = __attribute__((ext_vector_type(4))) float;

__device__ __forceinline__ unsigned short f2b(float f) {
  unsigned int u = __builtin_bit_cast(unsigned int, f);
  u += 0x7fffu + ((u >> 16) & 1u);   // RNE
  return (unsigned short)(u >> 16);
}

__device__ __forceinline__ float sigf(float x) {
  return 1.f / (1.f + __expf(-x));
}
__device__ __forceinline__ float tanh_f(float x) {
  return 2.f / (1.f + __expf(-2.f * x)) - 1.f;   // exact limits at +-inf
}

__device__ __forceinline__ void load_lds16(const void* g, void* l) {
  __builtin_amdgcn_global_load_lds(
      (const __attribute__((address_space(1))) void*)g,
      (__attribute__((address_space(3))) void*)(unsigned int)(unsigned long long)l,
      16, 0, 0);
}

#define MEMFENCE asm volatile("" ::: "memory")
#define BARRIER  do { MEMFENCE; __builtin_amdgcn_s_barrier(); MEMFENCE; } while (0)

// ---- fp32 -> bf16 convert (vectorized float4 -> ushort4) ----
__global__ void cvt_f32_bf16(const float* __restrict__ in,
                             unsigned short* __restrict__ out, int n4) {
  int i = blockIdx.x * blockDim.x + threadIdx.x;
  if (i >= n4) return;
  const float4 v = reinterpret_cast<const float4*>(in)[i];
  ushort4 u;
  u.x = f2b(v.x); u.y = f2b(v.y); u.z = f2b(v.z); u.w = f2b(v.w);
  reinterpret_cast<ushort4*>(out)[i] = u;
}

// ---- weight pack: W fp32 [4H,K] -> bf16 MFMA-fragment-major:
//  flat16B id = ((((bn*ntk + kt)*2 + wn)*6 + nf)*2 + kh)*64 + lane
//  frag content: lane l holds row n0+(l&15), k = kt*64 + kh*32 + (l>>4)*8 .. +8
//  where n0 = orig-gate-row(og)*1024 + chunk*16, chunk = bn*4 + wn*2 + nf/3,
//  og = {i:0, g:2, o:3}[nf%3]. ----
__global__ void pack_w(const float* __restrict__ W,
                       unsigned short* __restrict__ P, int K, int ntk) {
  long id = (long)blockIdx.x * blockDim.x + threadIdx.x;
  const long total = (long)NP * K / 8;
  if (id >= total) return;
  int l  = (int)(id & 63);
  long r = id >> 6;
  int kh = (int)(r & 1);   r >>= 1;
  int nf = (int)(r % 6);   r /= 6;
  int wn = (int)(r & 1);   r >>= 1;
  int kt = (int)(r % ntk); r /= ntk;
  int bn = (int)r;
  int hg = nf / 3, g3 = nf % 3;
  int chunk = bn * 4 + wn * 2 + hg;
  int og = (g3 == 0) ? 0 : (g3 == 1) ? 2 : 3;
  int srow = og * 1024 + chunk * 16 + (l & 15);
  int sk   = kt * 64 + kh * 32 + (l >> 4) * 8;
  const float* s = W + (long)srow * K + sk;
  const float4 v0 = *reinterpret_cast<const float4*>(s);
  const float4 v1 = *reinterpret_cast<const float4*>(s + 4);
  uint4 o;
  o.x = (unsigned)f2b(v0.x) | ((unsigned)f2b(v0.y) << 16);
  o.y = (unsigned)f2b(v0.z) | ((unsigned)f2b(v0.w) << 16);
  o.z = (unsigned)f2b(v1.x) | ((unsigned)f2b(v1.y) << 16);
  o.w = (unsigned)f2b(v1.z) | ((unsigned)f2b(v1.w) << 16);
  *reinterpret_cast<uint4*>(P + id * 8) = o;
}

__global__ void permute_b(const float* __restrict__ b, float* __restrict__ bp) {
  int np = blockIdx.x * blockDim.x + threadIdx.x;
  if (np >= NP) return;
  int chunk = np / 48, rem = np % 48;
  int g3 = rem >> 4, hl = rem & 15;
  int og = (g3 == 0) ? 0 : (g3 == 1) ? 2 : 3;
  bp[np] = b[og * 1024 + chunk * 16 + hl];
}

// ---- fused GEMM + gates; A via LDS (swizzled dbuf), B direct global->VGPR
//  from fragment-packed weights. Block 128x192, BK=64, 256 thr (4 waves 2Mx2N),
//  wave tile 64x96 (4 mf x 6 nf = 2 h-chunks x {i,g,o}), 48 MFMA / 1 barrier
//  per K-tile. LDS = 2 x 16KB (A only). B regs ping-pong (bE/bO), prefetch
//  depth 2, counted vmcnt(12) per tile: retires {A(t+1), B(t+1)}, leaves
//  B(t+2) in flight. ----
template <int MODE>  // 0: layer0 (bf16 out), 1: layer1 (fp32 out to d_out)
__global__ void __launch_bounds__(256, 2)
lstm_gemm(const unsigned short* __restrict__ A,
          const unsigned short* __restrict__ PF,
          const unsigned short* __restrict__ PB,
          const float* __restrict__ bpF, const float* __restrict__ bpB,
          int K,
          unsigned short* __restrict__ out_bf, float* __restrict__ out_f,
          float* __restrict__ hn, float* __restrict__ cn) {
  __shared__ __align__(16) char lds[32768];

  const int dir = blockIdx.z;
  const unsigned short* __restrict__ P = dir ? PB : PF;
  const float* __restrict__ bp = dir ? bpB : bpF;
  const int bm = blockIdx.y;   // 128-row band of A
  const int bn = blockIdx.x;   // 192-col band (4 h-chunks)

  const int tid  = threadIdx.x;
  const int wid  = tid >> 6;
  const int lane = tid & 63;
  const int wm   = wid >> 1;   // 0..1
  const int wn   = wid & 1;    // 0..1

  const int  nt = K >> 6;
  const long K2 = (long)K * 2;

  // A staging: linear LDS dest, pre-swizzled global source (slot = 8 rows x 1KB)
  const int rlane = lane >> 3;
  const int cb    = (((lane & 7) ^ rlane) << 4);
  const char* Asrc = (const char*)A + ((long)bm * 128 + rlane) * K2 + cb;

  // B fragment base: [bn][kt][wn][nf][kh][lane*16B], kt stride = 24576 B
  const char* Bbase = (const char*)P + (long)bn * nt * 24576 + wn * 12288 + lane * 16;

  // A ds_read constants (XOR-swizzled)
  const int l15 = lane & 15;
  const int hi  = lane >> 4;
  const int c0  = ((hi ^ (l15 & 7)) << 4);
  const int aro = (wm * 64 + l15) * 128;

  f32x4 acc[4][6];
  const f32x4 zero = {0.f, 0.f, 0.f, 0.f};
#pragma unroll
  for (int i = 0; i < 4; ++i)
#pragma unroll
    for (int j = 0; j < 6; ++j) acc[i][j] = zero;

  bf16x8 bE[6][2], bO[6][2];

  auto STAGE_A = [&](int t) {   // 4 x global_load_lds per thread
    if (t >= nt) return;
    char* d = lds + (t & 1) * 16384;
    const long off = (long)t * 128;
#pragma unroll
    for (int s = 0; s < 4; ++s) {
      const int slot = s * 4 + wid;
      load_lds16(Asrc + (long)(slot * 8) * K2 + off, d + slot * 1024);
    }
  };

#define LOADB(breg, t)                                                       \
  {                                                                          \
    const char* p_ = Bbase + (long)(t) * 24576;                              \
    _Pragma("unroll") for (int nf_ = 0; nf_ < 6; ++nf_)                      \
      _Pragma("unroll") for (int kh_ = 0; kh_ < 2; ++kh_)                    \
        breg[nf_][kh_] = *(const bf16x8*)(p_ + nf_ * 2048 + kh_ * 1024);     \
  }

  // prologue: A(0) then B(0) then B(1); fences pin vmcnt issue order
  STAGE_A(0);
  MEMFENCE;
  LOADB(bE, 0);
  MEMFENCE;
  LOADB(bO, 1);
  MEMFENCE;
  asm volatile("s_waitcnt vmcnt(12)" ::: "memory");   // A(0)+B(0) done
  BARRIER;

#define TILE(t, bcur)                                                        \
  {                                                                          \
    STAGE_A((t) + 1);                                                        \
    MEMFENCE;                                                                \
    const char* abuf = lds + ((t) & 1) * 16384 + aro;                        \
    bf16x8 a[4][2];                                                          \
    _Pragma("unroll") for (int mf = 0; mf < 4; ++mf) {                       \
      a[mf][0] = *(const bf16x8*)(abuf + mf * 2048 + c0);                    \
      a[mf][1] = *(const bf16x8*)(abuf + mf * 2048 + (c0 ^ 64));             \
    }                                                                        \
    __builtin_amdgcn_s_setprio(1);                                           \
    _Pragma("unroll") for (int mf = 0; mf < 4; ++mf)                         \
      _Pragma("unroll") for (int nf = 0; nf < 6; ++nf) {                     \
        acc[mf][nf] = __builtin_amdgcn_mfma_f32_16x16x32_bf16(               \
            a[mf][0], bcur[nf][0], acc[mf][nf], 0, 0, 0);                    \
        acc[mf][nf] = __builtin_amdgcn_mfma_f32_16x16x32_bf16(               \
            a[mf][1], bcur[nf][1], acc[mf][nf], 0, 0, 0);                    \
      }                                                                      \
    __builtin_amdgcn_s_setprio(0);                                           \
    if ((t) + 2 < nt) { LOADB(bcur, (t) + 2); }                              \
    MEMFENCE;                                                                \
    if ((t) < nt - 2) { asm volatile("s_waitcnt vmcnt(12)" ::: "memory"); }  \
    else              { asm volatile("s_waitcnt vmcnt(0)"  ::: "memory"); }  \
    BARRIER;                                                                 \
  }

  for (int t = 0; t < nt; t += 2) {   // nt is even (16 or 32)
    TILE(t, bE);
    TILE(t + 1, bO);
  }
#undef TILE
#undef LOADB

  // ---- epilogue: gates -> h (and h_n/c_n rows) ----
  const int col    = l15;
  const int rbase  = hi * 4;
  const int chunk0 = bn * 4 + wn * 2;
  const int Lidx   = MODE * 2 + dir;

#pragma unroll
  for (int hg = 0; hg < 2; ++hg) {
    const int chunk  = chunk0 + hg;
    const int h      = chunk * 16 + col;
    const int outcol = dir * HID + h;
    const float bi = bp[chunk * 48 + col];
    const float bg = bp[chunk * 48 + 16 + col];
    const float bo = bp[chunk * 48 + 32 + col];
#pragma unroll
    for (int mf = 0; mf < 4; ++mf) {
#pragma unroll
      for (int r = 0; r < 4; ++r) {
        const int m = bm * 128 + wm * 64 + mf * 16 + rbase + r;
        const float iv = acc[mf][hg * 3 + 0][r] + bi;
        const float gv = acc[mf][hg * 3 + 1][r] + bg;
        const float ov = acc[mf][hg * 3 + 2][r] + bo;
        const float is = sigf(iv);
        const float gt = tanh_f(gv);
        const float os = sigf(ov);
        const float c  = is * gt;
        const float hv = os * tanh_f(c);
        if (MODE == 0) {
          out_bf[(long)m * 2048 + outcol] = f2b(hv);
        } else {
          out_f[(long)m * 2048 + outcol] = hv;
        }
        const bool wst = (dir == 0) ? (m >= (S_LEN - 1) * BATCH) : (m < BATCH);
        if (wst) {
          const int b = (dir == 0) ? (m - (S_LEN - 1) * BATCH) : m;
          hn[((long)Lidx * BATCH + b) * HID + h] = hv;
          cn[((long)Lidx * BATCH + b) * HID + h] = c;
        }
      }
    }
  }
}

extern "C" void kernel_launch(void* const* d_in, const int* in_sizes, int n_in,
                              void* d_out, int out_size, void* d_ws, size_t ws_size,
                              hipStream_t stream) {
  const float* x    = (const float*)d_in[0];
  const float* W_f0 = (const float*)d_in[1];
  const float* b_f0 = (const float*)d_in[2];
  const float* W_b0 = (const float*)d_in[3];
  const float* b_b0 = (const float*)d_in[4];
  const float* W_f1 = (const float*)d_in[5];
  const float* b_f1 = (const float*)d_in[6];
  const float* W_b1 = (const float*)d_in[7];
  const float* b_b1 = (const float*)d_in[8];

  float* out = (float*)d_out;
  float* hn  = out + (long)MROWS * 2048;
  float* cn  = hn + 4 * BATCH * HID;

  unsigned short* x_bf  = (unsigned short*)d_ws;
  unsigned short* out1  = x_bf + (long)MROWS * 1024;
  unsigned short* wp_f0 = out1 + (long)MROWS * 2048;
  unsigned short* wp_b0 = wp_f0 + (long)NP * 1024;
  unsigned short* wp_f1 = wp_b0 + (long)NP * 1024;
  unsigned short* wp_b1 = wp_f1 + (long)NP * 2048;
  float* bp_f0 = (float*)(wp_b1 + (long)NP * 2048);
  float* bp_b0 = bp_f0 + NP;
  float* bp_f1 = bp_b0 + NP;
  float* bp_b1 = bp_f1 + NP;

  cvt_f32_bf16<<<16384, 256, 0, stream>>>(x, x_bf, MROWS * 1024 / 4);
  pack_w<<<1536, 256, 0, stream>>>(W_f0, wp_f0, 1024, 16);
  pack_w<<<1536, 256, 0, stream>>>(W_b0, wp_b0, 1024, 16);
  pack_w<<<3072, 256, 0, stream>>>(W_f1, wp_f1, 2048, 32);
  pack_w<<<3072, 256, 0, stream>>>(W_b1, wp_b1, 2048, 32);
  permute_b<<<12, 256, 0, stream>>>(b_f0, bp_f0);
  permute_b<<<12, 256, 0, stream>>>(b_b0, bp_b0);
  permute_b<<<12, 256, 0, stream>>>(b_f1, bp_f1);
  permute_b<<<12, 256, 0, stream>>>(b_b1, bp_b1);

  dim3 grid(NP / 192, MROWS / 128, 2);
  lstm_gemm<0><<<grid, 256, 0, stream>>>(x_bf, wp_f0, wp_b0, bp_f0, bp_b0, 1024,
                                         out1, nullptr, hn, cn);
  lstm_gemm<1><<<grid, 256, 0, stream>>>(out1, wp_f1, wp_b1, bp_f1, bp_b1, 2048,
                                         nullptr, out, hn, cn);
}